// Round 4
// baseline (519.274 us; speedup 1.0000x reference)
//
#include <hip/hip_runtime.h>

#define B_   8
#define C_   256
#define TC_  512
#define HW_  2304   // 48*48
#define EPS_ 1e-6f

typedef __bf16 bf16_t;
typedef __bf16 bf16x8 __attribute__((ext_vector_type(8)));
typedef float  f32x4 __attribute__((ext_vector_type(4)));
typedef unsigned int  u32;
typedef long long     i64;
typedef unsigned char u8;

__device__ __forceinline__ u8 to_fp8(float v) {
    return (u8)(__builtin_amdgcn_cvt_pk_fp8_f32(v, v, 0, false) & 0xff);
}

// ---------------------------------------------------------------------------
// W -> fragment-major bf16.  For frag f=(ot,ks) of matrix W[CO][CIN], lane l
// (l16=l&15, quad=l>>4) owns W[(ot*16+l16)*CIN + ks*32 + quad*8 .. +8).
// Output: Wlin[f*512 + l*8]  (512 bf16 = 1 KB per frag) -> the conv kernels
// load each frag as ONE coalesced 1-KB wave read instead of 16 scattered
// 64-B lines.  Frags: Wq 16x8=128 | Wk 16x16=256 | Wv 16x16=256.
// ---------------------------------------------------------------------------
__global__ __launch_bounds__(256)
void wfrag_kernel(const float* __restrict__ wq, const float* __restrict__ wk,
                  const float* __restrict__ wv,
                  bf16_t* __restrict__ oq, bf16_t* __restrict__ ok,
                  bf16_t* __restrict__ ov)
{
    const int fid = blockIdx.x * 4 + (threadIdx.x >> 6);   // 0..639
    const int lane = threadIdx.x & 63;
    const int l16 = lane & 15, quad = lane >> 4;

    const float* src; bf16_t* dst; int cin, f;
    if (fid < 128)      { src = wq; dst = oq; cin = C_;  f = fid; }
    else if (fid < 384) { src = wk; dst = ok; cin = TC_; f = fid - 128; }
    else                { src = wv; dst = ov; cin = TC_; f = fid - 384; }
    const int nks = cin / 32;
    const int ot = f / nks, ks = f % nks;

    const float* s = src + (size_t)(ot * 16 + l16) * cin + ks * 32 + quad * 8;
    float4 a = *(const float4*)(s);
    float4 b = *(const float4*)(s + 4);
    bf16x8 o;
    o[0] = (__bf16)a.x; o[1] = (__bf16)a.y; o[2] = (__bf16)a.z; o[3] = (__bf16)a.w;
    o[4] = (__bf16)b.x; o[5] = (__bf16)b.y; o[6] = (__bf16)b.z; o[7] = (__bf16)b.w;
    *(bf16x8*)(dst + (size_t)f * 512 + lane * 8) = o;
}

// ---------------------------------------------------------------------------
// Fused 1x1-conv stage, o-split, fp8 direct output, frag-major W.
// bid: b = bid&7 (XCD affinity), n0 = (bid>>3)*16.
// outA fp8 [b][n][C] = normalize_o(Wa X); outV fp8 [b][o][n] = Wv X.
// ---------------------------------------------------------------------------
template<int CIN, bool DO_V>
__global__ __launch_bounds__(256, 4)
void convqkv_kernel(const float* __restrict__ X, const bf16_t* __restrict__ Wa,
                    const bf16_t* __restrict__ Wvp, u8* __restrict__ outA,
                    u8* __restrict__ outV)
{
    const int bid = blockIdx.x;
    const int b  = bid & 7;
    const int n0 = (bid >> 3) * 16;
    const int tid = threadIdx.x;
    const int wv = tid >> 6;
    const int lane = tid & 63;
    const int quad = lane >> 4, l16 = lane & 15;
    const int NKS = CIN / 32;

    __shared__ bf16_t T[16][CIN + 8];
    __shared__ float ssp[4][16];

    // ---- stage: fp32 [c][n] -> bf16 T[n][c] ----
    {
        const float* Xb = X + (size_t)b * CIN * HW_ + n0;
        const int cl = tid >> 2;          // 0..63
        const int n4 = (tid & 3) * 4;     // 0,4,8,12
#pragma unroll
        for (int cp = 0; cp < CIN; cp += 64) {
            float4 v = *(const float4*)(Xb + (size_t)(cp + cl) * HW_ + n4);
            T[n4 + 0][cp + cl] = (__bf16)v.x;
            T[n4 + 1][cp + cl] = (__bf16)v.y;
            T[n4 + 2][cp + cl] = (__bf16)v.z;
            T[n4 + 3][cp + cl] = (__bf16)v.w;
        }
    }
    __syncthreads();

    // ---- all 16 px rows into registers ----
    bf16x8 af[CIN / 32];
#pragma unroll
    for (int ks = 0; ks < CIN / 32; ks++)
        af[ks] = *(const bf16x8*)(&T[l16][ks * 32 + quad * 8]);

    const int ot0 = wv * 4;

    // ---- K-GEMM (ks outer, p inner; coalesced frag loads) ----
    f32x4 accK[4];
#pragma unroll
    for (int p = 0; p < 4; p++) accK[p] = (f32x4){0.f, 0.f, 0.f, 0.f};
    {
        const bf16_t* wbase = Wa + ((size_t)ot0 * NKS) * 512 + lane * 8;
#pragma unroll
        for (int ks = 0; ks < CIN / 32; ks++)
#pragma unroll
            for (int p = 0; p < 4; p++) {
                bf16x8 bw = *(const bf16x8*)(wbase + (size_t)(p * NKS + ks) * 512);
                accK[p] = __builtin_amdgcn_mfma_f32_16x16x32_bf16(af[ks], bw, accK[p], 0, 0, 0);
            }
    }

    // ---- per-wave partial sum of squares over this wave's 64 o ----
    {
        float ssr[4];
#pragma unroll
        for (int r = 0; r < 4; r++) {
            float ss = accK[0][r] * accK[0][r] + accK[1][r] * accK[1][r]
                     + accK[2][r] * accK[2][r] + accK[3][r] * accK[3][r];
            ss += __shfl_xor(ss, 1);
            ss += __shfl_xor(ss, 2);
            ss += __shfl_xor(ss, 4);
            ss += __shfl_xor(ss, 8);
            ssr[r] = ss;
        }
        if (l16 == 0) {
#pragma unroll
            for (int r = 0; r < 4; r++) ssp[wv][quad * 4 + r] = ssr[r];
        }
    }

    // ---- V-GEMM (hides the ssp barrier) ----
    f32x4 accV[4];
    if (DO_V) {
#pragma unroll
        for (int p = 0; p < 4; p++) accV[p] = (f32x4){0.f, 0.f, 0.f, 0.f};
        const bf16_t* wbase = Wvp + ((size_t)ot0 * NKS) * 512 + lane * 8;
#pragma unroll
        for (int ks = 0; ks < CIN / 32; ks++)
#pragma unroll
            for (int p = 0; p < 4; p++) {
                bf16x8 aw = *(const bf16x8*)(wbase + (size_t)(p * NKS + ks) * 512);
                accV[p] = __builtin_amdgcn_mfma_f32_16x16x32_bf16(aw, af[ks], accV[p], 0, 0, 0);
            }
    }

    __syncthreads();

    // ---- combine norm partials, scale, write fp8 q/k ----
    float scale[4];
#pragma unroll
    for (int r = 0; r < 4; r++) {
        int px = quad * 4 + r;
        float s = ssp[0][px] + ssp[1][px] + ssp[2][px] + ssp[3][px];
        scale[r] = 1.0f / fmaxf(sqrtf(s), EPS_);
    }
    {
        // row = px = quad*4+r, col = o = (ot0+p)*16 + l16
        u8* oa = outA + ((size_t)b * HW_ + n0 + quad * 4) * C_ + l16;
#pragma unroll
        for (int p = 0; p < 4; p++)
#pragma unroll
            for (int r = 0; r < 4; r++)
                oa[(size_t)r * C_ + (ot0 + p) * 16] = to_fp8(accK[p][r] * scale[r]);
    }

    if (DO_V) {
        // row = o = (ot0+p)*16 + quad*4 + r, col = px = n0 + l16
#pragma unroll
        for (int p = 0; p < 4; p++)
#pragma unroll
            for (int r = 0; r < 4; r++)
                outV[((size_t)b * C_ + (ot0 + p) * 16 + quad * 4 + r) * HW_ + n0 + l16]
                    = to_fp8(accV[p][r]);
    }
}

// ---------------------------------------------------------------------------
// ROUND 4 (= round-3 design, resubmitted after infra failure):
// fully fused attention, LDS-staging-free.
//  * Block = (b, n0): 16 q-rows.  Grid = B*HW/16 = 1152, b = bid&7 keeps
//    batch->XCD affinity so K/V (1.2 MB/batch fp8) stay L2-resident.
//  * The 4 waves take disjoint interleaved j-stripes (tiles 4s+wv, s<18),
//    covering ALL 2304 j per block -> no split-J, no Opart/lpart, softmax
//    denominator complete in-block, epilogue (x + alpha*O/l) fused here.
//  * K/V fragments load DIRECTLY from L2 with b64 loads (same bytes the old
//    LDS decode produced).  No g2l16, no Kbuf/Vbuf, no per-tile barriers,
//    no vmcnt(0) drains; the 1.06e7 LDS-conflict cycles disappear.
//  * Cross-wave O reduction: pairwise through 33 KB f32 LDS, 2 barriers,
//    once per block; epilogue split across all 4 waves by ct-quarter.
// ---------------------------------------------------------------------------
__global__ __launch_bounds__(256, 3)
void attn_fused_kernel(const u8* __restrict__ q8, const u8* __restrict__ k8,
                       const u8* __restrict__ v8, const float* __restrict__ x,
                       const float* __restrict__ alphaPtr, float* __restrict__ out)
{
    const int bid = blockIdx.x;
    const int b   = bid & 7;
    const int n0  = (bid >> 3) * 16;
    const int wv   = threadIdx.x >> 6;
    const int lane = threadIdx.x & 63;
    const int quad = lane >> 4;
    const int l16  = lane & 15;

    const u8* qb = q8 + (size_t)b * HW_ * C_;
    const u8* kb = k8 + (size_t)b * HW_ * C_;
    const u8* vb = v8 + (size_t)b * C_ * HW_;

    __shared__ float Rb[2][16][260];   // pad 260: rows 4 banks apart
    __shared__ float lsb[4][16];

    // Q fragment: A lane(l16,quad) = q8[n0+l16][quad*8 + t*32 ..+8]
    i64 aq[8];
    {
        const u8* qr = qb + (size_t)(n0 + l16) * C_ + quad * 8;
#pragma unroll
        for (int t = 0; t < 8; t++) aq[t] = *(const i64*)(qr + t * 32);
    }

    f32x4 O[16];
#pragma unroll
    for (int i = 0; i < 16; i++) O[i] = (f32x4){0.f, 0.f, 0.f, 0.f};
    float lsum = 0.f;

#pragma unroll 1
    for (int s = 0; s < HW_ / 128; s++) {        // 18 tiles per wave
        const int j0 = (s * 4 + wv) * 32;
        const u8* kr0 = kb + (size_t)(j0 + l16) * C_ + quad * 8;
        const u8* kr1 = kr0 + 16 * C_;
        const u8* vr  = vb + (size_t)l16 * HW_ + j0 + quad * 8;

        // S^T = K . Q^T : lane (l16,quad) gets S[qrow=l16][j0 + quad*4 + r]
        f32x4 s00 = (f32x4){0.f,0.f,0.f,0.f}, s01 = (f32x4){0.f,0.f,0.f,0.f};
#pragma unroll
        for (int t = 0; t < 8; t++) {
            i64 bk0 = *(const i64*)(kr0 + t * 32);
            i64 bk1 = *(const i64*)(kr1 + t * 32);
            s00 = __builtin_amdgcn_mfma_f32_16x16x32_fp8_fp8(bk0, aq[t], s00, 0, 0, 0);
            s01 = __builtin_amdgcn_mfma_f32_16x16x32_fp8_fp8(bk1, aq[t], s01, 0, 0, 0);
        }

        // exp + fp8 pack for q-row l16: A = P[l16][j0+4q+0..3], B = +16
        float pA0 = __expf(s00[0] * 0.0625f), pA1 = __expf(s00[1] * 0.0625f);
        float pA2 = __expf(s00[2] * 0.0625f), pA3 = __expf(s00[3] * 0.0625f);
        float pB0 = __expf(s01[0] * 0.0625f), pB1 = __expf(s01[1] * 0.0625f);
        float pB2 = __expf(s01[2] * 0.0625f), pB3 = __expf(s01[3] * 0.0625f);
        lsum += (pA0 + pA1 + pA2 + pA3) + (pB0 + pB1 + pB2 + pB3);

        u32 A  = __builtin_amdgcn_cvt_pk_fp8_f32(pA0, pA1, 0, false);
        A      = __builtin_amdgcn_cvt_pk_fp8_f32(pA2, pA3, A, true);
        u32 Bw = __builtin_amdgcn_cvt_pk_fp8_f32(pB0, pB1, 0, false);
        Bw     = __builtin_amdgcn_cvt_pk_fp8_f32(pB2, pB3, Bw, true);

        // in-register transpose -> PV A-fragment (j = quad*8 .. quad*8+7)
        asm volatile("v_permlane32_swap_b32 %0, %1" : "+v"(A), "+v"(Bw));
        asm volatile("v_permlane16_swap_b32 %0, %1" : "+v"(A), "+v"(Bw));
        i64 ap0 = ((i64)(u32)Bw << 32) | (i64)A;

        // PV: B lane(l16,quad) = V[j0+quad*8..+8][c = ct*16 + l16]
#pragma unroll
        for (int ct = 0; ct < 16; ct++) {
            i64 bv = *(const i64*)(vr + (size_t)ct * 16 * HW_);
            O[ct] = __builtin_amdgcn_mfma_f32_16x16x32_fp8_fp8(ap0, bv, O[ct], 0, 0, 0);
        }
    }

    // per-wave row-sum (combine the 4 quads of row l16)
    lsum += __shfl_xor(lsum, 16);
    lsum += __shfl_xor(lsum, 32);
    if (quad == 0) lsb[wv][l16] = lsum;

    // ---- pairwise cross-wave O reduction through LDS ----
    if (wv & 1) {                       // waves 1,3 deposit
        float (*R)[260] = Rb[wv >> 1];
#pragma unroll
        for (int ct = 0; ct < 16; ct++)
#pragma unroll
            for (int r = 0; r < 4; r++)
                R[quad * 4 + r][ct * 16 + l16] = O[ct][r];
    }
    __syncthreads();
    if (!(wv & 1)) {                    // waves 0,2 accumulate + re-deposit
        float (*R)[260] = Rb[wv >> 1];
#pragma unroll
        for (int ct = 0; ct < 16; ct++)
#pragma unroll
            for (int r = 0; r < 4; r++) {
                float v = O[ct][r] + R[quad * 4 + r][ct * 16 + l16];
                R[quad * 4 + r][ct * 16 + l16] = v;
            }
    }
    __syncthreads();

    // ---- fused epilogue: out = x + alpha * O / l  (wave wv does ct-quarter) ----
    const float a = *alphaPtr;
    float lt[4];
#pragma unroll
    for (int r = 0; r < 4; r++) {
        int row = quad * 4 + r;
        lt[r] = lsb[0][row] + lsb[1][row] + lsb[2][row] + lsb[3][row];
    }
    const float* xb = x   + (size_t)b * C_ * HW_ + n0;
    float*       ob = out + (size_t)b * C_ * HW_ + n0;
#pragma unroll
    for (int ci = 0; ci < 4; ci++) {
        int ct = wv * 4 + ci;
        int c  = ct * 16 + l16;
        f32x4 xv = *(const f32x4*)(xb + (size_t)c * HW_ + quad * 4);
        f32x4 rv;
#pragma unroll
        for (int r = 0; r < 4; r++) {
            float ov = Rb[0][quad * 4 + r][ct * 16 + l16]
                     + Rb[1][quad * 4 + r][ct * 16 + l16];
            rv[r] = xv[r] + a * ov / lt[r];
        }
        *(f32x4*)(ob + (size_t)c * HW_ + quad * 4) = rv;
    }
}

// ---------------------------------------------------------------------------
extern "C" void kernel_launch(void* const* d_in, const int* in_sizes, int n_in,
                              void* d_out, int out_size, void* d_ws, size_t ws_size,
                              hipStream_t stream)
{
    (void)in_sizes; (void)n_in; (void)out_size; (void)ws_size;
    const float* x     = (const float*)d_in[0];
    const float* token = (const float*)d_in[1];
    const float* Wq    = (const float*)d_in[2];
    const float* Wk    = (const float*)d_in[3];
    const float* Wv    = (const float*)d_in[4];
    const float* alpha = (const float*)d_in[5];
    float* out = (float*)d_out;

    const size_t S = (size_t)B_ * HW_ * C_;   // 4,718,592 elements

    char* ws = (char*)d_ws;
    bf16_t* WqL = (bf16_t*)(ws + 6 * S);       // frag-major, 128 KB
    bf16_t* WkL = WqL + (size_t)C_ * C_;       // frag-major, 256 KB
    bf16_t* WvL = WkL + (size_t)C_ * TC_;      // frag-major, 256 KB
    u8*     q8  = (u8*)(ws + 7 * S);           // fp8 [b][n][C]
    u8*     k8  = (u8*)(ws + 8 * S);           // fp8 [b][n][C]
    u8*     v8  = (u8*)(ws + 9 * S);           // fp8 [b][C][n]

    wfrag_kernel<<<dim3(160), dim3(256), 0, stream>>>(Wq, Wk, Wv, WqL, WkL, WvL);
    convqkv_kernel<C_,  false><<<dim3(B_ * HW_ / 16), dim3(256), 0, stream>>>(x,     WqL, nullptr, q8, nullptr);
    convqkv_kernel<TC_, true ><<<dim3(B_ * HW_ / 16), dim3(256), 0, stream>>>(token, WkL, WvL,     k8, v8);
    attn_fused_kernel<<<dim3(B_ * HW_ / 16), dim3(256), 0, stream>>>(q8, k8, v8, x, alpha, out);
}

// Round 5
// 248.095 us; speedup vs baseline: 2.0930x; 2.0930x over previous
//
#include <hip/hip_runtime.h>

#define B_   8
#define C_   256
#define TC_  512
#define HW_  2304   // 48*48
#define EPS_ 1e-6f

typedef __bf16 bf16_t;
typedef __bf16 bf16x8 __attribute__((ext_vector_type(8)));
typedef __bf16 bf16x4_t __attribute__((ext_vector_type(4)));
typedef float  f32x4 __attribute__((ext_vector_type(4)));
typedef unsigned int  u32;
typedef long long     i64;
typedef unsigned char u8;

// async 16B global->LDS; lds dest is wave-uniform base (lane i -> base+16i)
__device__ __forceinline__ void g2l16(const void* g, void* l) {
    __builtin_amdgcn_global_load_lds(
        (const __attribute__((address_space(1))) unsigned int*)g,
        (__attribute__((address_space(3))) unsigned int*)l, 16, 0, 0);
}

__device__ __forceinline__ u8 to_fp8(float v) {
    return (u8)(__builtin_amdgcn_cvt_pk_fp8_f32(v, v, 0, false) & 0xff);
}

// ---------------------------------------------------------------------------
// W -> fragment-major bf16.  For frag f=(ot,ks) of matrix W[CO][CIN], lane l
// (l16=l&15, quad=l>>4) owns W[(ot*16+l16)*CIN + ks*32 + quad*8 .. +8).
// Output: Wlin[f*512 + l*8]  (512 bf16 = 1 KB per frag) -> the conv kernels
// load each frag as ONE coalesced 1-KB wave read instead of 16 scattered
// 64-B lines.  Frags: Wq 16x8=128 | Wk 16x16=256 | Wv 16x16=256.
// ---------------------------------------------------------------------------
__global__ __launch_bounds__(256)
void wfrag_kernel(const float* __restrict__ wq, const float* __restrict__ wk,
                  const float* __restrict__ wv,
                  bf16_t* __restrict__ oq, bf16_t* __restrict__ ok,
                  bf16_t* __restrict__ ov)
{
    const int fid = blockIdx.x * 4 + (threadIdx.x >> 6);   // 0..639
    const int lane = threadIdx.x & 63;
    const int l16 = lane & 15, quad = lane >> 4;

    const float* src; bf16_t* dst; int cin, f;
    if (fid < 128)      { src = wq; dst = oq; cin = C_;  f = fid; }
    else if (fid < 384) { src = wk; dst = ok; cin = TC_; f = fid - 128; }
    else                { src = wv; dst = ov; cin = TC_; f = fid - 384; }
    const int nks = cin / 32;
    const int ot = f / nks, ks = f % nks;

    const float* s = src + (size_t)(ot * 16 + l16) * cin + ks * 32 + quad * 8;
    float4 a = *(const float4*)(s);
    float4 b = *(const float4*)(s + 4);
    bf16x8 o;
    o[0] = (__bf16)a.x; o[1] = (__bf16)a.y; o[2] = (__bf16)a.z; o[3] = (__bf16)a.w;
    o[4] = (__bf16)b.x; o[5] = (__bf16)b.y; o[6] = (__bf16)b.z; o[7] = (__bf16)b.w;
    *(bf16x8*)(dst + (size_t)f * 512 + lane * 8) = o;
}

// ---------------------------------------------------------------------------
// Fused 1x1-conv stage, o-split, fp8 direct output, frag-major W.
// bid: b = bid&7 (XCD affinity), n0 = (bid>>3)*16.
// outA fp8 [b][n][C] = normalize_o(Wa X); outV fp8 [b][o][n] = Wv X.
// ---------------------------------------------------------------------------
template<int CIN, bool DO_V>
__global__ __launch_bounds__(256, 4)
void convqkv_kernel(const float* __restrict__ X, const bf16_t* __restrict__ Wa,
                    const bf16_t* __restrict__ Wvp, u8* __restrict__ outA,
                    u8* __restrict__ outV)
{
    const int bid = blockIdx.x;
    const int b  = bid & 7;
    const int n0 = (bid >> 3) * 16;
    const int tid = threadIdx.x;
    const int wv = tid >> 6;
    const int lane = tid & 63;
    const int quad = lane >> 4, l16 = lane & 15;
    const int NKS = CIN / 32;

    __shared__ bf16_t T[16][CIN + 8];
    __shared__ float ssp[4][16];

    // ---- stage: fp32 [c][n] -> bf16 T[n][c] ----
    {
        const float* Xb = X + (size_t)b * CIN * HW_ + n0;
        const int cl = tid >> 2;          // 0..63
        const int n4 = (tid & 3) * 4;     // 0,4,8,12
#pragma unroll
        for (int cp = 0; cp < CIN; cp += 64) {
            float4 v = *(const float4*)(Xb + (size_t)(cp + cl) * HW_ + n4);
            T[n4 + 0][cp + cl] = (__bf16)v.x;
            T[n4 + 1][cp + cl] = (__bf16)v.y;
            T[n4 + 2][cp + cl] = (__bf16)v.z;
            T[n4 + 3][cp + cl] = (__bf16)v.w;
        }
    }
    __syncthreads();

    // ---- all 16 px rows into registers ----
    bf16x8 af[CIN / 32];
#pragma unroll
    for (int ks = 0; ks < CIN / 32; ks++)
        af[ks] = *(const bf16x8*)(&T[l16][ks * 32 + quad * 8]);

    const int ot0 = wv * 4;

    // ---- K-GEMM (ks outer, p inner; coalesced frag loads) ----
    f32x4 accK[4];
#pragma unroll
    for (int p = 0; p < 4; p++) accK[p] = (f32x4){0.f, 0.f, 0.f, 0.f};
    {
        const bf16_t* wbase = Wa + ((size_t)ot0 * NKS) * 512 + lane * 8;
#pragma unroll
        for (int ks = 0; ks < CIN / 32; ks++)
#pragma unroll
            for (int p = 0; p < 4; p++) {
                bf16x8 bw = *(const bf16x8*)(wbase + (size_t)(p * NKS + ks) * 512);
                accK[p] = __builtin_amdgcn_mfma_f32_16x16x32_bf16(af[ks], bw, accK[p], 0, 0, 0);
            }
    }

    // ---- per-wave partial sum of squares over this wave's 64 o ----
    {
        float ssr[4];
#pragma unroll
        for (int r = 0; r < 4; r++) {
            float ss = accK[0][r] * accK[0][r] + accK[1][r] * accK[1][r]
                     + accK[2][r] * accK[2][r] + accK[3][r] * accK[3][r];
            ss += __shfl_xor(ss, 1);
            ss += __shfl_xor(ss, 2);
            ss += __shfl_xor(ss, 4);
            ss += __shfl_xor(ss, 8);
            ssr[r] = ss;
        }
        if (l16 == 0) {
#pragma unroll
            for (int r = 0; r < 4; r++) ssp[wv][quad * 4 + r] = ssr[r];
        }
    }

    // ---- V-GEMM (hides the ssp barrier) ----
    f32x4 accV[4];
    if (DO_V) {
#pragma unroll
        for (int p = 0; p < 4; p++) accV[p] = (f32x4){0.f, 0.f, 0.f, 0.f};
        const bf16_t* wbase = Wvp + ((size_t)ot0 * NKS) * 512 + lane * 8;
#pragma unroll
        for (int ks = 0; ks < CIN / 32; ks++)
#pragma unroll
            for (int p = 0; p < 4; p++) {
                bf16x8 aw = *(const bf16x8*)(wbase + (size_t)(p * NKS + ks) * 512);
                accV[p] = __builtin_amdgcn_mfma_f32_16x16x32_bf16(aw, af[ks], accV[p], 0, 0, 0);
            }
    }

    __syncthreads();

    // ---- combine norm partials, scale, write fp8 q/k ----
    float scale[4];
#pragma unroll
    for (int r = 0; r < 4; r++) {
        int px = quad * 4 + r;
        float s = ssp[0][px] + ssp[1][px] + ssp[2][px] + ssp[3][px];
        scale[r] = 1.0f / fmaxf(sqrtf(s), EPS_);
    }
    {
        // row = px = quad*4+r, col = o = (ot0+p)*16 + l16
        u8* oa = outA + ((size_t)b * HW_ + n0 + quad * 4) * C_ + l16;
#pragma unroll
        for (int p = 0; p < 4; p++)
#pragma unroll
            for (int r = 0; r < 4; r++)
                oa[(size_t)r * C_ + (ot0 + p) * 16] = to_fp8(accK[p][r] * scale[r]);
    }

    if (DO_V) {
        // row = o = (ot0+p)*16 + quad*4 + r, col = px = n0 + l16
#pragma unroll
        for (int p = 0; p < 4; p++)
#pragma unroll
            for (int r = 0; r < 4; r++)
                outV[((size_t)b * C_ + (ot0 + p) * 16 + quad * 4 + r) * HW_ + n0 + l16]
                    = to_fp8(accV[p][r]);
    }
}

// ---------------------------------------------------------------------------
// ROUND 5: round-2 staged attention + three measured fixes.
//  (1) Conflict-free K/V LDS layouts (the real fix for the 1.06e7 counter):
//      K slot = i*64 + 2*row_local + chunk_half  (chunk = 16B of a row)
//      V slot = ct-major: 2*c_local + chunk_half
//      staged via pre-permuted GLOBAL source (g2l16 dest stays linear).
//      Reads become l16*32+quad*8 (+512 / +ct*512): bank audit = 16B/bank
//      across all 32 banks = 4-cycle minimum, uniform.  Content bytes are
//      identical to round-2's fragments (verified by index algebra).
//  (2) Depth-2 prefetch with counted vmcnt + raw barrier (T3/T4):
//      3 buffers; per iter: wait vmcnt(4) [own tile-tt landed, tt+1 in
//      flight] -> s_barrier [all waves' tile-tt ready; all done reading
//      buf[(tt+2)%3]] -> STAGE(tt+2) -> compute(tt).  Only the last tile
//      ever drains vmcnt(0).
//  (3) s_setprio(1) around the MFMA clusters (T5; attn-positive, m191).
//  LDS = 3*(8K+8K) = 48 KB -> 3 blocks/CU.
// ---------------------------------------------------------------------------
__global__ __launch_bounds__(256, 3)
void attn_part_kernel(const u8* __restrict__ q8, const u8* __restrict__ k8,
                      const u8* __restrict__ v8,
                      bf16_t* __restrict__ Opart, float* __restrict__ lpart,
                      int tilesPerSplit, int JS)
{
    const int bid = blockIdx.x;
    const int b   = bid & 7;
    const int rr  = bid >> 3;
    const int js  = rr % JS;
    const int mt  = rr / JS;
    const int wv   = threadIdx.x >> 6;
    const int lane = threadIdx.x & 63;
    const int quad = lane >> 4;
    const int l16  = lane & 15;
    const int row0 = mt * 64 + wv * 16;
    const int jbase = js * tilesPerSplit * 32;

    const u8* qb = q8 + (size_t)b * HW_ * C_;
    const u8* kb = k8 + (size_t)b * HW_ * C_;
    const u8* vb = v8 + (size_t)b * C_ * HW_;

    __shared__ u8 Kbuf[3][8192];
    __shared__ u8 Vbuf[3][8192];

    i64 aq[8];
    {
        const u8* r0 = qb + (size_t)(row0 + l16) * C_ + quad * 8;
#pragma unroll
        for (int t = 0; t < 8; t++) aq[t] = *(const i64*)(r0 + t * 32);
    }

    f32x4 O[16];
#pragma unroll
    for (int i = 0; i < 16; i++) O[i] = (f32x4){0.f, 0.f, 0.f, 0.f};
    float lsum = 0.f;

    const int rl = lane >> 1;         // row_local (K) / c_local-sub (V)
    const int ch = lane & 1;          // chunk half

    // K: slot i*64 + 2*(j-row) + half  <- k8[j0+rl][i*32 + ch*16 .. +16]
    // V: slot i*64 + lane = 2*(i*32+rl) + ch <- v8[c=i*32+rl][j0 + ch*16 ..]
#define STAGE(bufi, j0g)                                                       \
    {                                                                          \
        _Pragma("unroll")                                                      \
        for (int p = 0; p < 2; p++) {                                          \
            int i = wv * 2 + p;                                                \
            g2l16(kb + (size_t)((j0g) + rl) * C_ + i * 32 + ch * 16,           \
                  &Kbuf[bufi][i * 1024]);                                      \
        }                                                                      \
        _Pragma("unroll")                                                      \
        for (int p = 0; p < 2; p++) {                                          \
            int i = wv * 2 + p;                                                \
            g2l16(vb + (size_t)(i * 32 + rl) * HW_ + (j0g) + ch * 16,          \
                  &Vbuf[bufi][i * 1024]);                                      \
        }                                                                      \
    }

    STAGE(0, jbase)
    STAGE(1, jbase + 32)

    const int koff = l16 * 32 + quad * 8;   // conflict-free fragment offset

    for (int tt = 0; tt < tilesPerSplit; tt++) {
        // own tile-tt loads complete (tile tt+1 stays in flight)
        if (tt + 1 < tilesPerSplit) {
            asm volatile("s_waitcnt vmcnt(4)" ::: "memory");
        } else {
            asm volatile("s_waitcnt vmcnt(0)" ::: "memory");
        }
        __builtin_amdgcn_s_barrier();   // all waves' tile-tt data ready;
                                        // all waves done reading buf[(tt+2)%3]
        if (tt + 2 < tilesPerSplit)
            STAGE((tt + 2) % 3, jbase + (tt + 2) * 32)
        __builtin_amdgcn_sched_barrier(0);

        const u8* Kb = Kbuf[tt % 3];
        const u8* Vb = Vbuf[tt % 3];

        // S^T = K . Q^T : lane (l16,quad) accumulates S[qrow=l16][j=quad*4+r]
        f32x4 s00 = (f32x4){0.f,0.f,0.f,0.f}, s01 = (f32x4){0.f,0.f,0.f,0.f};
        __builtin_amdgcn_s_setprio(1);
#pragma unroll
        for (int t = 0; t < 8; t++) {
            i64 bk0 = *(const i64*)(Kb + t * 1024 + koff);
            i64 bk1 = *(const i64*)(Kb + t * 1024 + koff + 512);
            s00 = __builtin_amdgcn_mfma_f32_16x16x32_fp8_fp8(bk0, aq[t], s00, 0, 0, 0);
            s01 = __builtin_amdgcn_mfma_f32_16x16x32_fp8_fp8(bk1, aq[t], s01, 0, 0, 0);
        }
        __builtin_amdgcn_s_setprio(0);

        // exp + fp8 pack, all for q-row l16:
        //   A bytes = P[l16][4q+0..3], B bytes = P[l16][16+4q+0..3]
        float pA0 = __expf(s00[0] * 0.0625f), pA1 = __expf(s00[1] * 0.0625f);
        float pA2 = __expf(s00[2] * 0.0625f), pA3 = __expf(s00[3] * 0.0625f);
        float pB0 = __expf(s01[0] * 0.0625f), pB1 = __expf(s01[1] * 0.0625f);
        float pB2 = __expf(s01[2] * 0.0625f), pB3 = __expf(s01[3] * 0.0625f);
        lsum += (pA0 + pA1 + pA2 + pA3) + (pB0 + pB1 + pB2 + pB3);

        u32 A  = __builtin_amdgcn_cvt_pk_fp8_f32(pA0, pA1, 0, false);
        A      = __builtin_amdgcn_cvt_pk_fp8_f32(pA2, pA3, A, true);
        u32 Bw = __builtin_amdgcn_cvt_pk_fp8_f32(pB0, pB1, 0, false);
        Bw     = __builtin_amdgcn_cvt_pk_fp8_f32(pB2, pB3, Bw, true);

        // in-register transpose to PV A-fragment (j = quad*8 .. quad*8+7)
        asm volatile("v_permlane32_swap_b32 %0, %1" : "+v"(A), "+v"(Bw));
        asm volatile("v_permlane16_swap_b32 %0, %1" : "+v"(A), "+v"(Bw));
        i64 ap0 = ((i64)(u32)Bw << 32) | (i64)A;

        __builtin_amdgcn_s_setprio(1);
#pragma unroll
        for (int ct = 0; ct < 16; ct++) {
            i64 bv = *(const i64*)(Vb + ct * 512 + koff);
            O[ct] = __builtin_amdgcn_mfma_f32_16x16x32_fp8_fp8(ap0, bv, O[ct], 0, 0, 0);
        }
        __builtin_amdgcn_s_setprio(0);
    }

    // row sum: combine the 4 quads of column l16
    lsum += __shfl_xor(lsum, 16);
    lsum += __shfl_xor(lsum, 32);
    float* lp = lpart + (size_t)(js * B_ + b) * HW_;
    if (quad == 0) lp[row0 + l16] = lsum;

    bf16_t* op = Opart + (size_t)(js * B_ + b) * C_ * HW_;
#pragma unroll
    for (int ct = 0; ct < 16; ct++) {
        int c = ct * 16 + l16;
        bf16x4_t v0;
        v0[0] = (__bf16)O[ct][0]; v0[1] = (__bf16)O[ct][1];
        v0[2] = (__bf16)O[ct][2]; v0[3] = (__bf16)O[ct][3];
        *(bf16x4_t*)(op + (size_t)c * HW_ + row0 + quad * 4) = v0;
    }
#undef STAGE
}

// ---------------------------------------------------------------------------
// out[b][c][n] = x + alpha * (sum_js Opart) / (sum_js lpart[b][n])
// ---------------------------------------------------------------------------
__global__ __launch_bounds__(256)
void epilogue_kernel(const float* __restrict__ x, const bf16_t* __restrict__ Opart,
                     const float* __restrict__ lpart, const float* __restrict__ alphaPtr,
                     float* __restrict__ out, int JS)
{
    const float a = *alphaPtr;
    const size_t S = (size_t)B_ * C_ * HW_;
    size_t flat = ((size_t)blockIdx.x * 256 + threadIdx.x) * 4;
    int bc = (int)(flat / HW_);
    int n  = (int)(flat % HW_);
    int b  = bc >> 8;
    float4 xv = *(const float4*)(x + flat);
    float s0 = 0.f, s1 = 0.f, s2 = 0.f, s3 = 0.f;
    float l0 = 0.f, l1 = 0.f, l2 = 0.f, l3 = 0.f;
    for (int js = 0; js < JS; js++) {
        bf16x4_t ov = *(const bf16x4_t*)(Opart + (size_t)js * S + flat);
        s0 += (float)ov[0]; s1 += (float)ov[1];
        s2 += (float)ov[2]; s3 += (float)ov[3];
        float4 lv = *(const float4*)(lpart + (size_t)(js * B_ + b) * HW_ + n);
        l0 += lv.x; l1 += lv.y; l2 += lv.z; l3 += lv.w;
    }
    float4 r;
    r.x = xv.x + a * s0 / l0;
    r.y = xv.y + a * s1 / l1;
    r.z = xv.z + a * s2 / l2;
    r.w = xv.w + a * s3 / l3;
    *(float4*)(out + flat) = r;
}

// ---------------------------------------------------------------------------
extern "C" void kernel_launch(void* const* d_in, const int* in_sizes, int n_in,
                              void* d_out, int out_size, void* d_ws, size_t ws_size,
                              hipStream_t stream)
{
    (void)in_sizes; (void)n_in; (void)out_size;
    const float* x     = (const float*)d_in[0];
    const float* token = (const float*)d_in[1];
    const float* Wq    = (const float*)d_in[2];
    const float* Wk    = (const float*)d_in[3];
    const float* Wv    = (const float*)d_in[4];
    const float* alpha = (const float*)d_in[5];
    float* out = (float*)d_out;

    const size_t S = (size_t)B_ * HW_ * C_;   // 4,718,592 elements

    int JS = 4;
    for (;;) {
        size_t need = (12 + 2 * (size_t)JS) * S
                    + (size_t)JS * B_ * HW_ * 4 + (size_t)B_ * HW_ * 4;
        if (need <= ws_size || JS == 1) break;
        JS >>= 1;
    }
    const int tilesPerSplit = (HW_ / 32) / JS;  // 72/JS

    char* ws = (char*)d_ws;
    bf16_t* WqL   = (bf16_t*)(ws + 6 * S);       // frag-major, 128 KB
    bf16_t* WkL   = WqL + (size_t)C_ * C_;       // frag-major, 256 KB
    bf16_t* WvL   = WkL + (size_t)C_ * TC_;      // frag-major, 256 KB
    u8*     q8    = (u8*)(ws + 7 * S);           // fp8 [b][n][C]
    u8*     k8    = (u8*)(ws + 8 * S);           // fp8 [b][n][C]
    u8*     v8    = (u8*)(ws + 9 * S);           // fp8 [b][C][n]
    bf16_t* Opart = (bf16_t*)(ws + 12 * S);      // [js][b][c][n] bf16
    float*  lpart = (float*)(ws + (12 + 2 * (size_t)JS) * S);

    wfrag_kernel<<<dim3(160), dim3(256), 0, stream>>>(Wq, Wk, Wv, WqL, WkL, WvL);
    convqkv_kernel<C_,  false><<<dim3(B_ * HW_ / 16), dim3(256), 0, stream>>>(x,     WqL, nullptr, q8, nullptr);
    convqkv_kernel<TC_, true ><<<dim3(B_ * HW_ / 16), dim3(256), 0, stream>>>(token, WkL, WvL,     k8, v8);
    attn_part_kernel<<<dim3(JS * B_ * (HW_ / 64)), dim3(256), 0, stream>>>(q8, k8, v8, Opart, lpart, tilesPerSplit, JS);
    epilogue_kernel<<<dim3((int)(S / 1024)), dim3(256), 0, stream>>>(x, Opart, lpart, alpha, out, JS);
}

// Round 7
// 220.070 us; speedup vs baseline: 2.3596x; 1.1273x over previous
//
#include <hip/hip_runtime.h>

#define B_   8
#define C_   256
#define TC_  512
#define HW_  2304   // 48*48
#define EPS_ 1e-6f

typedef __bf16 bf16_t;
typedef __bf16 bf16x8 __attribute__((ext_vector_type(8)));
typedef __bf16 bf16x4_t __attribute__((ext_vector_type(4)));
typedef float  f32x4 __attribute__((ext_vector_type(4)));
typedef unsigned int  u32;
typedef long long     i64;
typedef unsigned char u8;

// async 16B global->LDS; lds dest is wave-uniform base (lane i -> base+16i)
__device__ __forceinline__ void g2l16(const void* g, void* l) {
    __builtin_amdgcn_global_load_lds(
        (const __attribute__((address_space(1))) unsigned int*)g,
        (__attribute__((address_space(3))) unsigned int*)l, 16, 0, 0);
}

__device__ __forceinline__ u8 to_fp8(float v) {
    return (u8)(__builtin_amdgcn_cvt_pk_fp8_f32(v, v, 0, false) & 0xff);
}

// ---------------------------------------------------------------------------
// W -> fragment-major bf16 (unchanged).
// ---------------------------------------------------------------------------
__global__ __launch_bounds__(256)
void wfrag_kernel(const float* __restrict__ wq, const float* __restrict__ wk,
                  const float* __restrict__ wv,
                  bf16_t* __restrict__ oq, bf16_t* __restrict__ ok,
                  bf16_t* __restrict__ ov)
{
    const int fid = blockIdx.x * 4 + (threadIdx.x >> 6);   // 0..639
    const int lane = threadIdx.x & 63;
    const int l16 = lane & 15, quad = lane >> 4;

    const float* src; bf16_t* dst; int cin, f;
    if (fid < 128)      { src = wq; dst = oq; cin = C_;  f = fid; }
    else if (fid < 384) { src = wk; dst = ok; cin = TC_; f = fid - 128; }
    else                { src = wv; dst = ov; cin = TC_; f = fid - 384; }
    const int nks = cin / 32;
    const int ot = f / nks, ks = f % nks;

    const float* s = src + (size_t)(ot * 16 + l16) * cin + ks * 32 + quad * 8;
    float4 a = *(const float4*)(s);
    float4 b = *(const float4*)(s + 4);
    bf16x8 o;
    o[0] = (__bf16)a.x; o[1] = (__bf16)a.y; o[2] = (__bf16)a.z; o[3] = (__bf16)a.w;
    o[4] = (__bf16)b.x; o[5] = (__bf16)b.y; o[6] = (__bf16)b.z; o[7] = (__bf16)b.w;
    *(bf16x8*)(dst + (size_t)f * 512 + lane * 8) = o;
}

// ---------------------------------------------------------------------------
// Fused 1x1-conv stage.  KFMT selects outA layout:
//   KFMT=0: q8  [b][n][C]                       (attn reads Q per-lane b64)
//   KFMT=1: k8' [b][cchunk=o/8][j=n][8 bytes]   (granule = 2 adjacent rows)
// DO_V writes v8' [b][jchunk=n/8][c=o][8 bytes].
// These layouts make attn's g2l16 staging granules (16 B = row-pair at one
// 8-B column chunk) globally contiguous -> conflict-free LDS reads.
// ---------------------------------------------------------------------------
template<int CIN, bool DO_V, bool KFMT>
__global__ __launch_bounds__(256, 4)
void convqkv_kernel(const float* __restrict__ X, const bf16_t* __restrict__ Wa,
                    const bf16_t* __restrict__ Wvp, u8* __restrict__ outA,
                    u8* __restrict__ outV)
{
    const int bid = blockIdx.x;
    const int b  = bid & 7;
    const int n0 = (bid >> 3) * 16;
    const int tid = threadIdx.x;
    const int wv = tid >> 6;
    const int lane = tid & 63;
    const int quad = lane >> 4, l16 = lane & 15;
    const int NKS = CIN / 32;

    __shared__ bf16_t T[16][CIN + 8];
    __shared__ float ssp[4][16];

    // ---- stage: fp32 [c][n] -> bf16 T[n][c] ----
    {
        const float* Xb = X + (size_t)b * CIN * HW_ + n0;
        const int cl = tid >> 2;          // 0..63
        const int n4 = (tid & 3) * 4;     // 0,4,8,12
#pragma unroll
        for (int cp = 0; cp < CIN; cp += 64) {
            float4 v = *(const float4*)(Xb + (size_t)(cp + cl) * HW_ + n4);
            T[n4 + 0][cp + cl] = (__bf16)v.x;
            T[n4 + 1][cp + cl] = (__bf16)v.y;
            T[n4 + 2][cp + cl] = (__bf16)v.z;
            T[n4 + 3][cp + cl] = (__bf16)v.w;
        }
    }
    __syncthreads();

    // ---- all 16 px rows into registers ----
    bf16x8 af[CIN / 32];
#pragma unroll
    for (int ks = 0; ks < CIN / 32; ks++)
        af[ks] = *(const bf16x8*)(&T[l16][ks * 32 + quad * 8]);

    const int ot0 = wv * 4;

    // ---- K-GEMM ----
    f32x4 accK[4];
#pragma unroll
    for (int p = 0; p < 4; p++) accK[p] = (f32x4){0.f, 0.f, 0.f, 0.f};
    {
        const bf16_t* wbase = Wa + ((size_t)ot0 * NKS) * 512 + lane * 8;
#pragma unroll
        for (int ks = 0; ks < CIN / 32; ks++)
#pragma unroll
            for (int p = 0; p < 4; p++) {
                bf16x8 bw = *(const bf16x8*)(wbase + (size_t)(p * NKS + ks) * 512);
                accK[p] = __builtin_amdgcn_mfma_f32_16x16x32_bf16(af[ks], bw, accK[p], 0, 0, 0);
            }
    }

    // ---- per-wave partial sum of squares over this wave's 64 o ----
    {
        float ssr[4];
#pragma unroll
        for (int r = 0; r < 4; r++) {
            float ss = accK[0][r] * accK[0][r] + accK[1][r] * accK[1][r]
                     + accK[2][r] * accK[2][r] + accK[3][r] * accK[3][r];
            ss += __shfl_xor(ss, 1);
            ss += __shfl_xor(ss, 2);
            ss += __shfl_xor(ss, 4);
            ss += __shfl_xor(ss, 8);
            ssr[r] = ss;
        }
        if (l16 == 0) {
#pragma unroll
            for (int r = 0; r < 4; r++) ssp[wv][quad * 4 + r] = ssr[r];
        }
    }

    // ---- V-GEMM (hides the ssp barrier) ----
    f32x4 accV[4];
    if (DO_V) {
#pragma unroll
        for (int p = 0; p < 4; p++) accV[p] = (f32x4){0.f, 0.f, 0.f, 0.f};
        const bf16_t* wbase = Wvp + ((size_t)ot0 * NKS) * 512 + lane * 8;
#pragma unroll
        for (int ks = 0; ks < CIN / 32; ks++)
#pragma unroll
            for (int p = 0; p < 4; p++) {
                bf16x8 aw = *(const bf16x8*)(wbase + (size_t)(p * NKS + ks) * 512);
                accV[p] = __builtin_amdgcn_mfma_f32_16x16x32_bf16(aw, af[ks], accV[p], 0, 0, 0);
            }
    }

    __syncthreads();

    // ---- combine norm partials, scale, write fp8 q/k ----
    float scale[4];
#pragma unroll
    for (int r = 0; r < 4; r++) {
        int px = quad * 4 + r;
        float s = ssp[0][px] + ssp[1][px] + ssp[2][px] + ssp[3][px];
        scale[r] = 1.0f / fmaxf(sqrtf(s), EPS_);
    }
    if (!KFMT) {
        // q8 [b][n][C]: row = px = quad*4+r, col = o = (ot0+p)*16 + l16
        u8* oa = outA + ((size_t)b * HW_ + n0 + quad * 4) * C_ + l16;
#pragma unroll
        for (int p = 0; p < 4; p++)
#pragma unroll
            for (int r = 0; r < 4; r++)
                oa[(size_t)r * C_ + (ot0 + p) * 16] = to_fp8(accK[p][r] * scale[r]);
    } else {
        // k8' [b][cc][j][8]: cc = o>>3 = (ot0+p)*2 + (l16>>3), byte = l16&7
        u8* oa = outA + (size_t)b * 32 * HW_ * 8;
#pragma unroll
        for (int p = 0; p < 4; p++)
#pragma unroll
            for (int r = 0; r < 4; r++)
                oa[(((size_t)((ot0 + p) * 2 + (l16 >> 3))) * HW_
                    + n0 + quad * 4 + r) * 8 + (l16 & 7)]
                    = to_fp8(accK[p][r] * scale[r]);
    }

    if (DO_V) {
        // v8' [b][jc][c][8]: jc = (n0+l16)>>3, c = o = (ot0+p)*16+quad*4+r
#pragma unroll
        for (int p = 0; p < 4; p++)
#pragma unroll
            for (int r = 0; r < 4; r++)
                outV[(((size_t)b * 288 + (n0 >> 3) + (l16 >> 3)) * 256
                      + (ot0 + p) * 16 + quad * 4 + r) * 8 + (l16 & 7)]
                    = to_fp8(accV[p][r]);
    }
}

// ---------------------------------------------------------------------------
// ROUND 7 (= round-6 design, resubmitted after infra failure):
// round-5 pipeline + PROVABLY conflict-free LDS reads.
// Counter model (calibrated r2/r5: 1.06e7 = 4 extra cyc/read, 3.19e7 = 12):
// wave64 b64 = 4-cycle min; N lanes/bank-pair within a 16-lane phase costs
// 4N cycles.  Fix: read addr = l16*8 + quad*128 (+512 bk1 / +ct*512 V):
// each phase (fixed quad) covers all 32 banks exactly once -> N=1.
// Staging granule (16 B) = row-pair (2m,2m+1) at one 8-B col-chunk, which
// the NEW k8'/v8' global layouts make contiguous; g2l16 dest stays linear.
//   K t-block (1024 B): bk0[quad*128+l16*8], bk1 at +512; staged from
//     k8'[cc = t*4 + (lw>>3)&3][j0 + (lw&7)*2 + (lw>=32)*16]
//   V inst-block i (1024 B): ct = 2i + (lw>=32); slot quad*128 + l16*8;
//     staged from v8'[jc = j0/8 + (lw>>3)&3][c = ct*16 + (lw&7)*2]
// Depth-2 prefetch (3 bufs), counted vmcnt(4), raw barrier, setprio kept.
// ---------------------------------------------------------------------------
__global__ __launch_bounds__(256, 3)
void attn_part_kernel(const u8* __restrict__ q8, const u8* __restrict__ k8,
                      const u8* __restrict__ v8,
                      bf16_t* __restrict__ Opart, float* __restrict__ lpart,
                      int tilesPerSplit, int JS)
{
    const int bid = blockIdx.x;
    const int b   = bid & 7;
    const int rr  = bid >> 3;
    const int js  = rr % JS;
    const int mt  = rr / JS;
    const int wv   = threadIdx.x >> 6;
    const int lane = threadIdx.x & 63;
    const int quad = lane >> 4;
    const int l16  = lane & 15;
    const int row0 = mt * 64 + wv * 16;
    const int jbase = js * tilesPerSplit * 32;

    const u8* qb = q8 + (size_t)b * HW_ * C_;
    const u8* kb = k8 + (size_t)b * 32 * HW_ * 8;    // k8' batch base
    const u8* vb = v8 + (size_t)b * 288 * 256 * 8;   // v8' batch base

    __shared__ u8 Kbuf[3][8192];
    __shared__ u8 Vbuf[3][8192];

    i64 aq[8];
    {
        const u8* r0 = qb + (size_t)(row0 + l16) * C_ + quad * 8;
#pragma unroll
        for (int t = 0; t < 8; t++) aq[t] = *(const i64*)(r0 + t * 32);
    }

    f32x4 O[16];
#pragma unroll
    for (int i = 0; i < 16; i++) O[i] = (f32x4){0.f, 0.f, 0.f, 0.f};
    float lsum = 0.f;

    // staging lane decomposition
    const int sQuad = (lane >> 3) & 3;   // col-chunk within t-block
    const int sRow2 = (lane & 7) * 2;    // row-pair base
    const int sHi   = lane >> 5;         // K: +16 rows | V: ct parity

#define STAGE(bufi, j0g)                                                       \
    {                                                                          \
        _Pragma("unroll")                                                      \
        for (int p = 0; p < 2; p++) {                                          \
            int i = wv * 2 + p;                                                \
            g2l16(kb + ((size_t)(i * 4 + sQuad) * HW_                          \
                        + (j0g) + sRow2 + sHi * 16) * 8,                       \
                  &Kbuf[bufi][i * 1024]);                                      \
        }                                                                      \
        _Pragma("unroll")                                                      \
        for (int p = 0; p < 2; p++) {                                          \
            int i = wv * 2 + p;                                                \
            g2l16(vb + (((size_t)((j0g) >> 3) + sQuad) * 256                   \
                        + (2 * i + sHi) * 16 + sRow2) * 8,                     \
                  &Vbuf[bufi][i * 1024]);                                      \
        }                                                                      \
    }

    STAGE(0, jbase)
    STAGE(1, jbase + 32)

    const int roff = quad * 128 + l16 * 8;   // conflict-free: phase covers all 32 banks

    for (int tt = 0; tt < tilesPerSplit; tt++) {
        if (tt + 1 < tilesPerSplit) {
            asm volatile("s_waitcnt vmcnt(4)" ::: "memory");
        } else {
            asm volatile("s_waitcnt vmcnt(0)" ::: "memory");
        }
        __builtin_amdgcn_s_barrier();   // tile tt ready; buf[(tt+2)%3] free
        if (tt + 2 < tilesPerSplit)
            STAGE((tt + 2) % 3, jbase + (tt + 2) * 32)
        __builtin_amdgcn_sched_barrier(0);

        const u8* Kb = Kbuf[tt % 3];
        const u8* Vb = Vbuf[tt % 3];

        // S^T = K . Q^T : lane (l16,quad) accumulates S[qrow=l16][j=quad*4+r]
        f32x4 s00 = (f32x4){0.f,0.f,0.f,0.f}, s01 = (f32x4){0.f,0.f,0.f,0.f};
        __builtin_amdgcn_s_setprio(1);
#pragma unroll
        for (int t = 0; t < 8; t++) {
            i64 bk0 = *(const i64*)(Kb + t * 1024 + roff);
            i64 bk1 = *(const i64*)(Kb + t * 1024 + roff + 512);
            s00 = __builtin_amdgcn_mfma_f32_16x16x32_fp8_fp8(bk0, aq[t], s00, 0, 0, 0);
            s01 = __builtin_amdgcn_mfma_f32_16x16x32_fp8_fp8(bk1, aq[t], s01, 0, 0, 0);
        }
        __builtin_amdgcn_s_setprio(0);

        // exp + fp8 pack, all for q-row l16
        float pA0 = __expf(s00[0] * 0.0625f), pA1 = __expf(s00[1] * 0.0625f);
        float pA2 = __expf(s00[2] * 0.0625f), pA3 = __expf(s00[3] * 0.0625f);
        float pB0 = __expf(s01[0] * 0.0625f), pB1 = __expf(s01[1] * 0.0625f);
        float pB2 = __expf(s01[2] * 0.0625f), pB3 = __expf(s01[3] * 0.0625f);
        lsum += (pA0 + pA1 + pA2 + pA3) + (pB0 + pB1 + pB2 + pB3);

        u32 A  = __builtin_amdgcn_cvt_pk_fp8_f32(pA0, pA1, 0, false);
        A      = __builtin_amdgcn_cvt_pk_fp8_f32(pA2, pA3, A, true);
        u32 Bw = __builtin_amdgcn_cvt_pk_fp8_f32(pB0, pB1, 0, false);
        Bw     = __builtin_amdgcn_cvt_pk_fp8_f32(pB2, pB3, Bw, true);

        // in-register transpose to PV A-fragment (j = quad*8 .. quad*8+7)
        asm volatile("v_permlane32_swap_b32 %0, %1" : "+v"(A), "+v"(Bw));
        asm volatile("v_permlane16_swap_b32 %0, %1" : "+v"(A), "+v"(Bw));
        i64 ap0 = ((i64)(u32)Bw << 32) | (i64)A;

        __builtin_amdgcn_s_setprio(1);
#pragma unroll
        for (int ct = 0; ct < 16; ct++) {
            i64 bv = *(const i64*)(Vb + ct * 512 + roff);
            O[ct] = __builtin_amdgcn_mfma_f32_16x16x32_fp8_fp8(ap0, bv, O[ct], 0, 0, 0);
        }
        __builtin_amdgcn_s_setprio(0);
    }

    // row sum: combine the 4 quads of column l16
    lsum += __shfl_xor(lsum, 16);
    lsum += __shfl_xor(lsum, 32);
    float* lp = lpart + (size_t)(js * B_ + b) * HW_;
    if (quad == 0) lp[row0 + l16] = lsum;

    bf16_t* op = Opart + (size_t)(js * B_ + b) * C_ * HW_;
#pragma unroll
    for (int ct = 0; ct < 16; ct++) {
        int c = ct * 16 + l16;
        bf16x4_t v0;
        v0[0] = (__bf16)O[ct][0]; v0[1] = (__bf16)O[ct][1];
        v0[2] = (__bf16)O[ct][2]; v0[3] = (__bf16)O[ct][3];
        *(bf16x4_t*)(op + (size_t)c * HW_ + row0 + quad * 4) = v0;
    }
#undef STAGE
}

// ---------------------------------------------------------------------------
// out[b][c][n] = x + alpha * (sum_js Opart) / (sum_js lpart[b][n])
// ---------------------------------------------------------------------------
__global__ __launch_bounds__(256)
void epilogue_kernel(const float* __restrict__ x, const bf16_t* __restrict__ Opart,
                     const float* __restrict__ lpart, const float* __restrict__ alphaPtr,
                     float* __restrict__ out, int JS)
{
    const float a = *alphaPtr;
    const size_t S = (size_t)B_ * C_ * HW_;
    size_t flat = ((size_t)blockIdx.x * 256 + threadIdx.x) * 4;
    int bc = (int)(flat / HW_);
    int n  = (int)(flat % HW_);
    int b  = bc >> 8;
    float4 xv = *(const float4*)(x + flat);
    float s0 = 0.f, s1 = 0.f, s2 = 0.f, s3 = 0.f;
    float l0 = 0.f, l1 = 0.f, l2 = 0.f, l3 = 0.f;
    for (int js = 0; js < JS; js++) {
        bf16x4_t ov = *(const bf16x4_t*)(Opart + (size_t)js * S + flat);
        s0 += (float)ov[0]; s1 += (float)ov[1];
        s2 += (float)ov[2]; s3 += (float)ov[3];
        float4 lv = *(const float4*)(lpart + (size_t)(js * B_ + b) * HW_ + n);
        l0 += lv.x; l1 += lv.y; l2 += lv.z; l3 += lv.w;
    }
    float4 r;
    r.x = xv.x + a * s0 / l0;
    r.y = xv.y + a * s1 / l1;
    r.z = xv.z + a * s2 / l2;
    r.w = xv.w + a * s3 / l3;
    *(float4*)(out + flat) = r;
}

// ---------------------------------------------------------------------------
extern "C" void kernel_launch(void* const* d_in, const int* in_sizes, int n_in,
                              void* d_out, int out_size, void* d_ws, size_t ws_size,
                              hipStream_t stream)
{
    (void)in_sizes; (void)n_in; (void)out_size;
    const float* x     = (const float*)d_in[0];
    const float* token = (const float*)d_in[1];
    const float* Wq    = (const float*)d_in[2];
    const float* Wk    = (const float*)d_in[3];
    const float* Wv    = (const float*)d_in[4];
    const float* alpha = (const float*)d_in[5];
    float* out = (float*)d_out;

    const size_t S = (size_t)B_ * HW_ * C_;   // 4,718,592 elements

    int JS = 4;
    for (;;) {
        size_t need = (12 + 2 * (size_t)JS) * S
                    + (size_t)JS * B_ * HW_ * 4 + (size_t)B_ * HW_ * 4;
        if (need <= ws_size || JS == 1) break;
        JS >>= 1;
    }
    const int tilesPerSplit = (HW_ / 32) / JS;  // 72/JS

    char* ws = (char*)d_ws;
    bf16_t* WqL   = (bf16_t*)(ws + 6 * S);       // frag-major, 128 KB
    bf16_t* WkL   = WqL + (size_t)C_ * C_;       // frag-major, 256 KB
    bf16_t* WvL   = WkL + (size_t)C_ * TC_;      // frag-major, 256 KB
    u8*     q8    = (u8*)(ws + 7 * S);           // fp8 [b][n][C]
    u8*     k8    = (u8*)(ws + 8 * S);           // fp8 k8' [b][cc][j][8]
    u8*     v8    = (u8*)(ws + 9 * S);           // fp8 v8' [b][jc][c][8]
    bf16_t* Opart = (bf16_t*)(ws + 12 * S);      // [js][b][c][n] bf16
    float*  lpart = (float*)(ws + (12 + 2 * (size_t)JS) * S);

    wfrag_kernel<<<dim3(160), dim3(256), 0, stream>>>(Wq, Wk, Wv, WqL, WkL, WvL);
    convqkv_kernel<C_,  false, false><<<dim3(B_ * HW_ / 16), dim3(256), 0, stream>>>(x,     WqL, nullptr, q8, nullptr);
    convqkv_kernel<TC_, true,  true ><<<dim3(B_ * HW_ / 16), dim3(256), 0, stream>>>(token, WkL, WvL,     k8, v8);
    attn_part_kernel<<<dim3(JS * B_ * (HW_ / 64)), dim3(256), 0, stream>>>(q8, k8, v8, Opart, lpart, tilesPerSplit, JS);
    epilogue_kernel<<<dim3((int)(S / 1024)), dim3(256), 0, stream>>>(x, Opart, lpart, alpha, out, JS);
}

// Round 8
// 219.008 us; speedup vs baseline: 2.3710x; 1.0048x over previous
//
#include <hip/hip_runtime.h>

#define B_   8
#define C_   256
#define TC_  512
#define HW_  2304   // 48*48
#define EPS_ 1e-6f

typedef __bf16 bf16_t;
typedef __bf16 bf16x8 __attribute__((ext_vector_type(8)));
typedef __bf16 bf16x4_t __attribute__((ext_vector_type(4)));
typedef float  f32x4 __attribute__((ext_vector_type(4)));
typedef unsigned int  u32;
typedef long long     i64;
typedef unsigned char u8;

// async 16B global->LDS; lds dest is wave-uniform base (lane i -> base+16i)
__device__ __forceinline__ void g2l16(const void* g, void* l) {
    __builtin_amdgcn_global_load_lds(
        (const __attribute__((address_space(1))) unsigned int*)g,
        (__attribute__((address_space(3))) unsigned int*)l, 16, 0, 0);
}

__device__ __forceinline__ u8 to_fp8(float v) {
    return (u8)(__builtin_amdgcn_cvt_pk_fp8_f32(v, v, 0, false) & 0xff);
}

// ---------------------------------------------------------------------------
// W -> fragment-major bf16 (unchanged).
// ---------------------------------------------------------------------------
__global__ __launch_bounds__(256)
void wfrag_kernel(const float* __restrict__ wq, const float* __restrict__ wk,
                  const float* __restrict__ wv,
                  bf16_t* __restrict__ oq, bf16_t* __restrict__ ok,
                  bf16_t* __restrict__ ov)
{
    const int fid = blockIdx.x * 4 + (threadIdx.x >> 6);   // 0..639
    const int lane = threadIdx.x & 63;
    const int l16 = lane & 15, quad = lane >> 4;

    const float* src; bf16_t* dst; int cin, f;
    if (fid < 128)      { src = wq; dst = oq; cin = C_;  f = fid; }
    else if (fid < 384) { src = wk; dst = ok; cin = TC_; f = fid - 128; }
    else                { src = wv; dst = ov; cin = TC_; f = fid - 384; }
    const int nks = cin / 32;
    const int ot = f / nks, ks = f % nks;

    const float* s = src + (size_t)(ot * 16 + l16) * cin + ks * 32 + quad * 8;
    float4 a = *(const float4*)(s);
    float4 b = *(const float4*)(s + 4);
    bf16x8 o;
    o[0] = (__bf16)a.x; o[1] = (__bf16)a.y; o[2] = (__bf16)a.z; o[3] = (__bf16)a.w;
    o[4] = (__bf16)b.x; o[5] = (__bf16)b.y; o[6] = (__bf16)b.z; o[7] = (__bf16)b.w;
    *(bf16x8*)(dst + (size_t)f * 512 + lane * 8) = o;
}

// ---------------------------------------------------------------------------
// Fused 1x1-conv stage.  KFMT selects outA layout:
//   KFMT=0: q8  [b][n][C]                       (attn reads Q per-lane b64)
//   KFMT=1: k8' [b][cchunk=o/8][j=n][8 bytes]   (granule = 2 adjacent rows)
// DO_V writes v8' [b][jchunk=n/8][c=o][8 bytes].
// These layouts make attn's g2l16 staging granules (16 B = row-pair at one
// 8-B column chunk) globally contiguous -> conflict-free LDS reads.
// ---------------------------------------------------------------------------
template<int CIN, bool DO_V, bool KFMT>
__global__ __launch_bounds__(256, 4)
void convqkv_kernel(const float* __restrict__ X, const bf16_t* __restrict__ Wa,
                    const bf16_t* __restrict__ Wvp, u8* __restrict__ outA,
                    u8* __restrict__ outV)
{
    const int bid = blockIdx.x;
    const int b  = bid & 7;
    const int n0 = (bid >> 3) * 16;
    const int tid = threadIdx.x;
    const int wv = tid >> 6;
    const int lane = tid & 63;
    const int quad = lane >> 4, l16 = lane & 15;
    const int NKS = CIN / 32;

    __shared__ bf16_t T[16][CIN + 8];
    __shared__ float ssp[4][16];

    // ---- stage: fp32 [c][n] -> bf16 T[n][c] ----
    {
        const float* Xb = X + (size_t)b * CIN * HW_ + n0;
        const int cl = tid >> 2;          // 0..63
        const int n4 = (tid & 3) * 4;     // 0,4,8,12
#pragma unroll
        for (int cp = 0; cp < CIN; cp += 64) {
            float4 v = *(const float4*)(Xb + (size_t)(cp + cl) * HW_ + n4);
            T[n4 + 0][cp + cl] = (__bf16)v.x;
            T[n4 + 1][cp + cl] = (__bf16)v.y;
            T[n4 + 2][cp + cl] = (__bf16)v.z;
            T[n4 + 3][cp + cl] = (__bf16)v.w;
        }
    }
    __syncthreads();

    // ---- all 16 px rows into registers ----
    bf16x8 af[CIN / 32];
#pragma unroll
    for (int ks = 0; ks < CIN / 32; ks++)
        af[ks] = *(const bf16x8*)(&T[l16][ks * 32 + quad * 8]);

    const int ot0 = wv * 4;

    // ---- K-GEMM ----
    f32x4 accK[4];
#pragma unroll
    for (int p = 0; p < 4; p++) accK[p] = (f32x4){0.f, 0.f, 0.f, 0.f};
    {
        const bf16_t* wbase = Wa + ((size_t)ot0 * NKS) * 512 + lane * 8;
#pragma unroll
        for (int ks = 0; ks < CIN / 32; ks++)
#pragma unroll
            for (int p = 0; p < 4; p++) {
                bf16x8 bw = *(const bf16x8*)(wbase + (size_t)(p * NKS + ks) * 512);
                accK[p] = __builtin_amdgcn_mfma_f32_16x16x32_bf16(af[ks], bw, accK[p], 0, 0, 0);
            }
    }

    // ---- per-wave partial sum of squares over this wave's 64 o ----
    {
        float ssr[4];
#pragma unroll
        for (int r = 0; r < 4; r++) {
            float ss = accK[0][r] * accK[0][r] + accK[1][r] * accK[1][r]
                     + accK[2][r] * accK[2][r] + accK[3][r] * accK[3][r];
            ss += __shfl_xor(ss, 1);
            ss += __shfl_xor(ss, 2);
            ss += __shfl_xor(ss, 4);
            ss += __shfl_xor(ss, 8);
            ssr[r] = ss;
        }
        if (l16 == 0) {
#pragma unroll
            for (int r = 0; r < 4; r++) ssp[wv][quad * 4 + r] = ssr[r];
        }
    }

    // ---- V-GEMM (hides the ssp barrier) ----
    f32x4 accV[4];
    if (DO_V) {
#pragma unroll
        for (int p = 0; p < 4; p++) accV[p] = (f32x4){0.f, 0.f, 0.f, 0.f};
        const bf16_t* wbase = Wvp + ((size_t)ot0 * NKS) * 512 + lane * 8;
#pragma unroll
        for (int ks = 0; ks < CIN / 32; ks++)
#pragma unroll
            for (int p = 0; p < 4; p++) {
                bf16x8 aw = *(const bf16x8*)(wbase + (size_t)(p * NKS + ks) * 512);
                accV[p] = __builtin_amdgcn_mfma_f32_16x16x32_bf16(aw, af[ks], accV[p], 0, 0, 0);
            }
    }

    __syncthreads();

    // ---- combine norm partials, scale, write fp8 q/k ----
    float scale[4];
#pragma unroll
    for (int r = 0; r < 4; r++) {
        int px = quad * 4 + r;
        float s = ssp[0][px] + ssp[1][px] + ssp[2][px] + ssp[3][px];
        scale[r] = 1.0f / fmaxf(sqrtf(s), EPS_);
    }
    if (!KFMT) {
        // q8 [b][n][C]: row = px = quad*4+r, col = o = (ot0+p)*16 + l16
        u8* oa = outA + ((size_t)b * HW_ + n0 + quad * 4) * C_ + l16;
#pragma unroll
        for (int p = 0; p < 4; p++)
#pragma unroll
            for (int r = 0; r < 4; r++)
                oa[(size_t)r * C_ + (ot0 + p) * 16] = to_fp8(accK[p][r] * scale[r]);
    } else {
        // k8' [b][cc][j][8]: cc = o>>3 = (ot0+p)*2 + (l16>>3), byte = l16&7
        u8* oa = outA + (size_t)b * 32 * HW_ * 8;
#pragma unroll
        for (int p = 0; p < 4; p++)
#pragma unroll
            for (int r = 0; r < 4; r++)
                oa[(((size_t)((ot0 + p) * 2 + (l16 >> 3))) * HW_
                    + n0 + quad * 4 + r) * 8 + (l16 & 7)]
                    = to_fp8(accK[p][r] * scale[r]);
    }

    if (DO_V) {
        // v8' [b][jc][c][8]: jc = (n0+l16)>>3, c = o = (ot0+p)*16+quad*4+r
#pragma unroll
        for (int p = 0; p < 4; p++)
#pragma unroll
            for (int r = 0; r < 4; r++)
                outV[(((size_t)b * 288 + (n0 >> 3) + (l16 >> 3)) * 256
                      + (ot0 + p) * 16 + quad * 4 + r) * 8 + (l16 & 7)]
                    = to_fp8(accV[p][r]);
    }
}

// ---------------------------------------------------------------------------
// ROUND 8: conflict-free layouts (r7, verified: conflicts == 0) + software
// pipelining of S one tile ahead.  Per iteration:
//   vmcnt(0) [tile tt+1 landed; only 4 loads outstanding, issued 1 iter ago]
//   s_barrier ; STAGE(tt+2)
//   QK(tt+1) -> sB      [MFMA chain, Kbuf[(tt+1)%3]]
//   exp/pack(sA=S(tt))  [VALU, overlaps QK in-flight]
//   PV(tt)              [MFMA, independent accumulators, Vbuf[tt%3]]
//   sA = sB
// The three phases are independent dep-chains -> MFMA pipe streams ~32
// back-to-back instead of serializing QK-latency -> exp -> PV (~265 cyc).
// Buffer liveness: iter tt touches buf[tt](PV), buf[tt+1](QK), buf[tt+2]
// (stage) = exactly the 3 buffers; WAR/RAW audited.  Static sA/sB swap.
// ---------------------------------------------------------------------------
__global__ __launch_bounds__(256, 3)
void attn_part_kernel(const u8* __restrict__ q8, const u8* __restrict__ k8,
                      const u8* __restrict__ v8,
                      bf16_t* __restrict__ Opart, float* __restrict__ lpart,
                      int tilesPerSplit, int JS)
{
    const int bid = blockIdx.x;
    const int b   = bid & 7;
    const int rr  = bid >> 3;
    const int js  = rr % JS;
    const int mt  = rr / JS;
    const int wv   = threadIdx.x >> 6;
    const int lane = threadIdx.x & 63;
    const int quad = lane >> 4;
    const int l16  = lane & 15;
    const int row0 = mt * 64 + wv * 16;
    const int jbase = js * tilesPerSplit * 32;

    const u8* qb = q8 + (size_t)b * HW_ * C_;
    const u8* kb = k8 + (size_t)b * 32 * HW_ * 8;    // k8' batch base
    const u8* vb = v8 + (size_t)b * 288 * 256 * 8;   // v8' batch base

    __shared__ u8 Kbuf[3][8192];
    __shared__ u8 Vbuf[3][8192];

    i64 aq[8];
    {
        const u8* r0 = qb + (size_t)(row0 + l16) * C_ + quad * 8;
#pragma unroll
        for (int t = 0; t < 8; t++) aq[t] = *(const i64*)(r0 + t * 32);
    }

    f32x4 O[16];
#pragma unroll
    for (int i = 0; i < 16; i++) O[i] = (f32x4){0.f, 0.f, 0.f, 0.f};
    float lsum = 0.f;

    // staging lane decomposition
    const int sQuad = (lane >> 3) & 3;   // col-chunk within t-block
    const int sRow2 = (lane & 7) * 2;    // row-pair base
    const int sHi   = lane >> 5;         // K: +16 rows | V: ct parity

#define STAGE(bufi, j0g)                                                       \
    {                                                                          \
        _Pragma("unroll")                                                      \
        for (int p = 0; p < 2; p++) {                                          \
            int i = wv * 2 + p;                                                \
            g2l16(kb + ((size_t)(i * 4 + sQuad) * HW_                          \
                        + (j0g) + sRow2 + sHi * 16) * 8,                       \
                  &Kbuf[bufi][i * 1024]);                                      \
        }                                                                      \
        _Pragma("unroll")                                                      \
        for (int p = 0; p < 2; p++) {                                          \
            int i = wv * 2 + p;                                                \
            g2l16(vb + (((size_t)((j0g) >> 3) + sQuad) * 256                   \
                        + (2 * i + sHi) * 16 + sRow2) * 8,                     \
                  &Vbuf[bufi][i * 1024]);                                      \
        }                                                                      \
    }

    STAGE(0, jbase)
    STAGE(1, jbase + 32)

    const int roff = quad * 128 + l16 * 8;   // conflict-free fragment offset

    // ---- prologue: QK(0) into sA ----
    f32x4 sA0, sA1;
    {
        asm volatile("s_waitcnt vmcnt(4)" ::: "memory");   // tile 0 landed
        __builtin_amdgcn_s_barrier();
        __builtin_amdgcn_sched_barrier(0);
        const u8* Kb = Kbuf[0];
        f32x4 a0 = (f32x4){0.f,0.f,0.f,0.f}, a1 = (f32x4){0.f,0.f,0.f,0.f};
        __builtin_amdgcn_s_setprio(1);
#pragma unroll
        for (int t = 0; t < 8; t++) {
            i64 bk0 = *(const i64*)(Kb + t * 1024 + roff);
            i64 bk1 = *(const i64*)(Kb + t * 1024 + roff + 512);
            a0 = __builtin_amdgcn_mfma_f32_16x16x32_fp8_fp8(bk0, aq[t], a0, 0, 0, 0);
            a1 = __builtin_amdgcn_mfma_f32_16x16x32_fp8_fp8(bk1, aq[t], a1, 0, 0, 0);
        }
        __builtin_amdgcn_s_setprio(0);
        sA0 = a0; sA1 = a1;
    }

    for (int tt = 0; tt < tilesPerSplit; tt++) {
        // tile tt+1 landed (its 4 loads were issued one full iteration ago)
        asm volatile("s_waitcnt vmcnt(0)" ::: "memory");
        __builtin_amdgcn_s_barrier();   // tile tt+1 globally ready;
                                        // buf[(tt+2)%3] free (last read iter tt-1)
        if (tt + 2 < tilesPerSplit)
            STAGE((tt + 2) % 3, jbase + (tt + 2) * 32)
        __builtin_amdgcn_sched_barrier(0);

        // ---- QK(tt+1) -> sB (independent of exp/PV below) ----
        f32x4 sB0 = (f32x4){0.f,0.f,0.f,0.f}, sB1 = (f32x4){0.f,0.f,0.f,0.f};
        if (tt + 1 < tilesPerSplit) {
            const u8* Kb = Kbuf[(tt + 1) % 3];
            __builtin_amdgcn_s_setprio(1);
#pragma unroll
            for (int t = 0; t < 8; t++) {
                i64 bk0 = *(const i64*)(Kb + t * 1024 + roff);
                i64 bk1 = *(const i64*)(Kb + t * 1024 + roff + 512);
                sB0 = __builtin_amdgcn_mfma_f32_16x16x32_fp8_fp8(bk0, aq[t], sB0, 0, 0, 0);
                sB1 = __builtin_amdgcn_mfma_f32_16x16x32_fp8_fp8(bk1, aq[t], sB1, 0, 0, 0);
            }
            __builtin_amdgcn_s_setprio(0);
        }

        // ---- exp + fp8 pack of S(tt) (VALU; overlaps QK in flight) ----
        float pA0 = __expf(sA0[0] * 0.0625f), pA1 = __expf(sA0[1] * 0.0625f);
        float pA2 = __expf(sA0[2] * 0.0625f), pA3 = __expf(sA0[3] * 0.0625f);
        float pB0 = __expf(sA1[0] * 0.0625f), pB1 = __expf(sA1[1] * 0.0625f);
        float pB2 = __expf(sA1[2] * 0.0625f), pB3 = __expf(sA1[3] * 0.0625f);
        lsum += (pA0 + pA1 + pA2 + pA3) + (pB0 + pB1 + pB2 + pB3);

        u32 A  = __builtin_amdgcn_cvt_pk_fp8_f32(pA0, pA1, 0, false);
        A      = __builtin_amdgcn_cvt_pk_fp8_f32(pA2, pA3, A, true);
        u32 Bw = __builtin_amdgcn_cvt_pk_fp8_f32(pB0, pB1, 0, false);
        Bw     = __builtin_amdgcn_cvt_pk_fp8_f32(pB2, pB3, Bw, true);

        // in-register transpose to PV A-fragment (j = quad*8 .. quad*8+7)
        asm volatile("v_permlane32_swap_b32 %0, %1" : "+v"(A), "+v"(Bw));
        asm volatile("v_permlane16_swap_b32 %0, %1" : "+v"(A), "+v"(Bw));
        i64 ap0 = ((i64)(u32)Bw << 32) | (i64)A;

        // ---- PV(tt) ----
        const u8* Vb = Vbuf[tt % 3];
        __builtin_amdgcn_s_setprio(1);
#pragma unroll
        for (int ct = 0; ct < 16; ct++) {
            i64 bv = *(const i64*)(Vb + ct * 512 + roff);
            O[ct] = __builtin_amdgcn_mfma_f32_16x16x32_fp8_fp8(ap0, bv, O[ct], 0, 0, 0);
        }
        __builtin_amdgcn_s_setprio(0);

        sA0 = sB0; sA1 = sB1;
    }

    // row sum: combine the 4 quads of column l16
    lsum += __shfl_xor(lsum, 16);
    lsum += __shfl_xor(lsum, 32);
    float* lp = lpart + (size_t)(js * B_ + b) * HW_;
    if (quad == 0) lp[row0 + l16] = lsum;

    bf16_t* op = Opart + (size_t)(js * B_ + b) * C_ * HW_;
#pragma unroll
    for (int ct = 0; ct < 16; ct++) {
        int c = ct * 16 + l16;
        bf16x4_t v0;
        v0[0] = (__bf16)O[ct][0]; v0[1] = (__bf16)O[ct][1];
        v0[2] = (__bf16)O[ct][2]; v0[3] = (__bf16)O[ct][3];
        *(bf16x4_t*)(op + (size_t)c * HW_ + row0 + quad * 4) = v0;
    }
#undef STAGE
}

// ---------------------------------------------------------------------------
// out[b][c][n] = x + alpha * (sum_js Opart) / (sum_js lpart[b][n])
// ---------------------------------------------------------------------------
__global__ __launch_bounds__(256)
void epilogue_kernel(const float* __restrict__ x, const bf16_t* __restrict__ Opart,
                     const float* __restrict__ lpart, const float* __restrict__ alphaPtr,
                     float* __restrict__ out, int JS)
{
    const float a = *alphaPtr;
    const size_t S = (size_t)B_ * C_ * HW_;
    size_t flat = ((size_t)blockIdx.x * 256 + threadIdx.x) * 4;
    int bc = (int)(flat / HW_);
    int n  = (int)(flat % HW_);
    int b  = bc >> 8;
    float4 xv = *(const float4*)(x + flat);
    float s0 = 0.f, s1 = 0.f, s2 = 0.f, s3 = 0.f;
    float l0 = 0.f, l1 = 0.f, l2 = 0.f, l3 = 0.f;
    for (int js = 0; js < JS; js++) {
        bf16x4_t ov = *(const bf16x4_t*)(Opart + (size_t)js * S + flat);
        s0 += (float)ov[0]; s1 += (float)ov[1];
        s2 += (float)ov[2]; s3 += (float)ov[3];
        float4 lv = *(const float4*)(lpart + (size_t)(js * B_ + b) * HW_ + n);
        l0 += lv.x; l1 += lv.y; l2 += lv.z; l3 += lv.w;
    }
    float4 r;
    r.x = xv.x + a * s0 / l0;
    r.y = xv.y + a * s1 / l1;
    r.z = xv.z + a * s2 / l2;
    r.w = xv.w + a * s3 / l3;
    *(float4*)(out + flat) = r;
}

// ---------------------------------------------------------------------------
extern "C" void kernel_launch(void* const* d_in, const int* in_sizes, int n_in,
                              void* d_out, int out_size, void* d_ws, size_t ws_size,
                              hipStream_t stream)
{
    (void)in_sizes; (void)n_in; (void)out_size;
    const float* x     = (const float*)d_in[0];
    const float* token = (const float*)d_in[1];
    const float* Wq    = (const float*)d_in[2];
    const float* Wk    = (const float*)d_in[3];
    const float* Wv    = (const float*)d_in[4];
    const float* alpha = (const float*)d_in[5];
    float* out = (float*)d_out;

    const size_t S = (size_t)B_ * HW_ * C_;   // 4,718,592 elements

    int JS = 4;
    for (;;) {
        size_t need = (12 + 2 * (size_t)JS) * S
                    + (size_t)JS * B_ * HW_ * 4 + (size_t)B_ * HW_ * 4;
        if (need <= ws_size || JS == 1) break;
        JS >>= 1;
    }
    const int tilesPerSplit = (HW_ / 32) / JS;  // 72/JS

    char* ws = (char*)d_ws;
    bf16_t* WqL   = (bf16_t*)(ws + 6 * S);       // frag-major, 128 KB
    bf16_t* WkL   = WqL + (size_t)C_ * C_;       // frag-major, 256 KB
    bf16_t* WvL   = WkL + (size_t)C_ * TC_;      // frag-major, 256 KB
    u8*     q8    = (u8*)(ws + 7 * S);           // fp8 [b][n][C]
    u8*     k8    = (u8*)(ws + 8 * S);           // fp8 k8' [b][cc][j][8]
    u8*     v8    = (u8*)(ws + 9 * S);           // fp8 v8' [b][jc][c][8]
    bf16_t* Opart = (bf16_t*)(ws + 12 * S);      // [js][b][c][n] bf16
    float*  lpart = (float*)(ws + (12 + 2 * (size_t)JS) * S);

    wfrag_kernel<<<dim3(160), dim3(256), 0, stream>>>(Wq, Wk, Wv, WqL, WkL, WvL);
    convqkv_kernel<C_,  false, false><<<dim3(B_ * HW_ / 16), dim3(256), 0, stream>>>(x,     WqL, nullptr, q8, nullptr);
    convqkv_kernel<TC_, true,  true ><<<dim3(B_ * HW_ / 16), dim3(256), 0, stream>>>(token, WkL, WvL,     k8, v8);
    attn_part_kernel<<<dim3(JS * B_ * (HW_ / 64)), dim3(256), 0, stream>>>(q8, k8, v8, Opart, lpart, tilesPerSplit, JS);
    epilogue_kernel<<<dim3((int)(S / 1024)), dim3(256), 0, stream>>>(x, Opart, lpart, alpha, out, JS);
}